// Round 5
// baseline (2326.270 us; speedup 1.0000x reference)
//
#include <hip/hip_runtime.h>

// Problem: B=8, L=1024, C=384, H=6, D=64, K=2(radial), N=4(angular)
// R5: MFMA GEMMs (verified) + hybrid attention (MFMA QK^T -> LDS S -> VALU PV).
typedef unsigned int  u32;
typedef unsigned short u16;
typedef __attribute__((ext_vector_type(8))) short short8;   // 8 bf16
typedef __attribute__((ext_vector_type(4))) float f32x4;

__device__ __forceinline__ u16 f2bf(float x) {
  union { float f; u32 u; } un; un.f = x;
  u32 r = un.u + 0x7FFFu + ((un.u >> 16) & 1u);   // RNE
  return (u16)(r >> 16);
}
__device__ __forceinline__ float bflo(u32 u) {
  union { u32 u; float f; } c; c.u = u << 16; return c.f;
}
__device__ __forceinline__ float bfhi(u32 u) {
  union { u32 u; float f; } c; c.u = u & 0xFFFF0000u; return c.f;
}
__device__ __forceinline__ f32x4 mfma_bf16(short8 a, short8 b, f32x4 c) {
  return __builtin_amdgcn_mfma_f32_16x16x32_bf16(a, b, c, 0, 0, 0);
}

// ---------------- prep: RMSNorm -> xn(bf16), convert w_in/w_out -> bf16 ----
__global__ __launch_bounds__(256) void prep_kernel(
    const float* __restrict__ x, const float* __restrict__ w_norm,
    const float* __restrict__ w_in, const float* __restrict__ w_out,
    u16* __restrict__ xn, u16* __restrict__ winb, u16* __restrict__ woutb)
{
  int blk = blockIdx.x, t = threadIdx.x;
  if (blk < 2048) {               // 8192 rows, 4 rows/block (1 per wave)
    int wv = t >> 6, lane = t & 63;
    int row = blk * 4 + wv;
    const float* xr = x + (size_t)row * 384;
    float v[6]; float ss = 0.f;
    #pragma unroll
    for (int i = 0; i < 6; i++) { v[i] = xr[lane + 64 * i]; ss += v[i] * v[i]; }
    #pragma unroll
    for (int off = 32; off > 0; off >>= 1) ss += __shfl_xor(ss, off);
    float rs = __builtin_amdgcn_rsqf(ss * (1.0f / 384.0f) + 1e-5f);
    #pragma unroll
    for (int i = 0; i < 6; i++) {
      float xv = v[i] * rs * w_norm[lane + 64 * i];
      xn[(size_t)row * 384 + lane + 64 * i] = f2bf(xv);
    }
  } else {                        // weight conversion: 442368 + 147456
    int base = (blk - 2048) * 2048 + t * 8;
    #pragma unroll
    for (int j = 0; j < 8; j++) {
      int idx = base + j;
      if (idx < 442368) winb[idx] = f2bf(w_in[idx]);
      else              woutb[idx - 442368] = f2bf(w_out[idx - 442368]);
    }
  }
}

// ---------------- MFMA GEMM: out[M,.] = A[M,K](lda)*Bw[N,K](ldb)^T + bias --
// 128x128 tile, BK=64, 4 waves (2x2), 16x16x32 bf16 MFMA, padded LDS. VERIFIED.
template<bool OUT_F32, bool QSCALE>
__global__ __launch_bounds__(256) void gemm_kernel(
    const u16* __restrict__ A, int lda,
    const u16* __restrict__ Bw, int ldb,
    const float* __restrict__ bias, void* __restrict__ outp, int ldc, int K)
{
  __shared__ __attribute__((aligned(16))) u16 As[128 * 72];
  __shared__ __attribute__((aligned(16))) u16 Bs[128 * 72];
  int t = threadIdx.x;
  int lane = t & 63, wv = t >> 6;
  int g = lane >> 4, cl = lane & 15;
  int row0 = blockIdx.x * 128, col0 = blockIdx.y * 128;
  int wm = (wv >> 1) * 64, wn = (wv & 1) * 64;
  f32x4 acc[4][4];
  #pragma unroll
  for (int i = 0; i < 4; i++)
    #pragma unroll
    for (int j = 0; j < 4; j++) acc[i][j] = (f32x4){0.f, 0.f, 0.f, 0.f};

  for (int k0 = 0; k0 < K; k0 += 64) {
    __syncthreads();
    #pragma unroll
    for (int j = 0; j < 4; j++) {
      int i = t + 256 * j;
      int r = i >> 3, ch = i & 7;
      *(uint4*)(&As[r * 72 + ch * 8]) =
          *(const uint4*)(A + (size_t)(row0 + r) * lda + k0 + ch * 8);
      *(uint4*)(&Bs[r * 72 + ch * 8]) =
          *(const uint4*)(Bw + (size_t)(col0 + r) * ldb + k0 + ch * 8);
    }
    __syncthreads();
    #pragma unroll
    for (int kh = 0; kh < 2; kh++) {
      short8 af[4], bfr[4];
      #pragma unroll
      for (int s = 0; s < 4; s++) {
        af[s]  = *(const short8*)(&As[(wm + s * 16 + cl) * 72 + kh * 32 + g * 8]);
        bfr[s] = *(const short8*)(&Bs[(wn + s * 16 + cl) * 72 + kh * 32 + g * 8]);
      }
      #pragma unroll
      for (int i = 0; i < 4; i++)
        #pragma unroll
        for (int j = 0; j < 4; j++)
          acc[i][j] = mfma_bf16(af[i], bfr[j], acc[i][j]);
    }
  }
  // epilogue: C/D layout col=lane&15, row=4*(lane>>4)+r  [HW-verified R4]
  #pragma unroll
  for (int i = 0; i < 4; i++) {
    #pragma unroll
    for (int j = 0; j < 4; j++) {
      int colb = col0 + wn + j * 16 + cl;
      float bv = bias[colb];
      #pragma unroll
      for (int r = 0; r < 4; r++) {
        int rowb = row0 + wm + i * 16 + g * 4 + r;
        float v = acc[i][j][r] + bv;
        if (QSCALE) { if (colb < 384) v *= 0.125f; }   // fold 1/sqrt(D) into Q
        if (OUT_F32) ((float*)outp)[(size_t)rowb * ldc + colb] = v;
        else ((u16*)outp)[(size_t)rowb * ldc + colb] = f2bf(v);
      }
    }
  }
}

// ---------------- hybrid attention ----------------------------------------
// Block = (b, h, 64 q-rows), 256 threads / 4 waves, 16 tiles of 64 keys.
// Phase 1 (per tile): wave wv computes S for q-rows wv*16..+15 via MFMA QK^T,
//   adds polar bias at D-layout (row=4g+r, col=cl), stores f32 S to LDS.
// Phase 2 (per tile): thread (ql=t&63, kg=t>>6) owns q-row ql, keys kg*16..+15;
//   private online softmax + VALU PV (R4-verified semantics).
// End: R4-verified 4-way LDS merge.
__global__ __launch_bounds__(256) void attn_hybrid(
    const u16* __restrict__ qkv, const float* __restrict__ pos,
    const float* __restrict__ bcf, const float* __restrict__ ccf,
    u16* __restrict__ obuf)
{
  __shared__ float buf[3][64][65];   // buf[0] = S-tile during loop; all 3 = merge osh
  __shared__ float msh[4][64];
  __shared__ float lsh[4][64];
  int blk = blockIdx.x;              // b*96 + h*16 + qt
  int qt = blk & 15, h = (blk >> 4) % 6, b = blk / 96;
  int t = threadIdx.x, lane = t & 63, wv = t >> 6;
  int g = lane >> 4, cl = lane & 15;
  int ql = t & 63, kg = t >> 6;      // phase-2 identity

  float bc[15], cc[15];
  #pragma unroll
  for (int i = 0; i < 15; i++) { bc[i] = bcf[h * 15 + i]; cc[i] = ccf[h * 15 + i]; }

  // Q fragments (A-operand): wave's rows wv*16+cl; Q pre-scaled by 1/8 in GEMM1
  const u16* qbase = qkv + (size_t)(b * 1024 + qt * 64 + wv * 16 + cl) * 1152 + h * 64;
  short8 qf0 = *(const short8*)(qbase + g * 8);
  short8 qf1 = *(const short8*)(qbase + 32 + g * 8);

  // bias q positions for this lane's output rows (4g+r within wave strip)
  float qx[4], qy[4];
  #pragma unroll
  for (int r = 0; r < 4; r++) {
    int qr = qt * 64 + wv * 16 + 4 * g + r;
    qx[r] = pos[(size_t)(b * 1024 + qr) * 2 + 0];
    qy[r] = pos[(size_t)(b * 1024 + qr) * 2 + 1];
  }

  // phase-2 private state
  float o[64];
  #pragma unroll
  for (int c = 0; c < 64; c++) o[c] = 0.f;
  float m = -1e30f, l = 0.f;

  const u16* kb = qkv + (size_t)b * 1024 * 1152 + 384 + h * 64;
  const float* pb = pos + (size_t)b * 2048;

  for (int k0 = 0; k0 < 1024; k0 += 64) {
    // ---- phase 1: S = (Q/8)K^T + bias -> buf[0] ----
    f32x4 s[4];
    #pragma unroll
    for (int ks = 0; ks < 4; ks++) {
      const u16* kr = kb + (size_t)(k0 + ks * 16 + cl) * 1152;
      short8 kf0 = *(const short8*)(kr + g * 8);
      short8 kf1 = *(const short8*)(kr + 32 + g * 8);
      f32x4 z = (f32x4){0.f, 0.f, 0.f, 0.f};
      z = mfma_bf16(qf0, kf0, z);
      z = mfma_bf16(qf1, kf1, z);
      s[ks] = z;
    }
    #pragma unroll
    for (int ks = 0; ks < 4; ks++) {
      int kidx = k0 + ks * 16 + cl;
      float kx = pb[kidx * 2], ky = pb[kidx * 2 + 1];
      #pragma unroll
      for (int r = 0; r < 4; r++) {
        float dx = qx[r] - kx, dy = qy[r] - ky;
        float r2 = dx * dx + dy * dy;
        bool zz = !(r2 > 0.f);
        float ir = zz ? 0.f : __builtin_amdgcn_rsqf(r2);
        float rr = r2 * ir;
        float c1 = zz ? 1.f : dx * ir;
        float s1 = dy * ir;
        float c2 = c1*c1 - s1*s1, s2 = 2.f*c1*s1;
        float c3 = c1*c2 - s1*s2, s3 = s1*c2 + c1*s2;
        float c4 = c2*c2 - s2*s2, s4 = 2.f*c2*s2;
        float a0 = bc[0] + bc[1]*c1 + bc[2]*c2 + bc[3]*c3 + bc[4]*c4
                 + cc[1]*s1 + cc[2]*s2 + cc[3]*s3 + cc[4]*s4;
        float a1 = bc[5] + bc[6]*c1 + bc[7]*c2 + bc[8]*c3 + bc[9]*c4
                 + cc[6]*s1 + cc[7]*s2 + cc[8]*s3 + cc[9]*s4;
        float a2 = bc[10] + bc[11]*c1 + bc[12]*c2 + bc[13]*c3 + bc[14]*c4
                 + cc[11]*s1 + cc[12]*s2 + cc[13]*s3 + cc[14]*s4;
        buf[0][wv * 16 + 4 * g + r][ks * 16 + cl] =
            s[ks][r] + a0 + rr * (a1 + rr * a2);
      }
    }
    __syncthreads();
    // ---- phase 2: online softmax + VALU PV over this thread's 16 keys ----
    float sv[16];
    float tmax = -1e30f;
    #pragma unroll
    for (int j = 0; j < 16; j++) {
      sv[j] = buf[0][ql][kg * 16 + j];
      tmax = fmaxf(tmax, sv[j]);
    }
    float mn = fmaxf(m, tmax);
    float sc = __builtin_amdgcn_exp2f((m - mn) * 1.44269504f);
    m = mn;
    float psum = 0.f;
    #pragma unroll
    for (int j = 0; j < 16; j++) {
      sv[j] = __builtin_amdgcn_exp2f((sv[j] - mn) * 1.44269504f);
      psum += sv[j];
    }
    l = l * sc + psum;
    #pragma unroll
    for (int c = 0; c < 64; c++) o[c] *= sc;
    #pragma unroll
    for (int j = 0; j < 16; j++) {
      const uint4* vr = (const uint4*)(
          qkv + (size_t)(b * 1024 + k0 + kg * 16 + j) * 1152 + 768 + h * 64);
      float pj = sv[j];
      #pragma unroll
      for (int c8 = 0; c8 < 8; c8++) {
        uint4 w = vr[c8];
        o[c8*8+0] += pj * bflo(w.x);
        o[c8*8+1] += pj * bfhi(w.x);
        o[c8*8+2] += pj * bflo(w.y);
        o[c8*8+3] += pj * bfhi(w.y);
        o[c8*8+4] += pj * bflo(w.z);
        o[c8*8+5] += pj * bfhi(w.z);
        o[c8*8+6] += pj * bflo(w.w);
        o[c8*8+7] += pj * bfhi(w.w);
      }
    }
    __syncthreads();
  }
  // ---- merge the 4 key-group partials (R4-verified) ----
  msh[kg][ql] = m;
  __syncthreads();
  float M = fmaxf(fmaxf(msh[0][ql], msh[1][ql]), fmaxf(msh[2][ql], msh[3][ql]));
  float f = __builtin_amdgcn_exp2f((m - M) * 1.44269504f);
  lsh[kg][ql] = l * f;
  if (kg > 0) {
    #pragma unroll
    for (int c = 0; c < 64; c++) buf[kg - 1][ql][c] = o[c] * f;
  }
  __syncthreads();
  if (kg == 0) {
    float lt = lsh[0][ql] + lsh[1][ql] + lsh[2][ql] + lsh[3][ql];
    float inv = __builtin_amdgcn_rcpf(lt);
    u16* orow = obuf + (size_t)(b * 1024 + qt * 64 + ql) * 384 + h * 64;
    #pragma unroll
    for (int c = 0; c < 64; c++) {
      float ot = o[c] * f + buf[0][ql][c] + buf[1][ql][c] + buf[2][ql][c];
      orow[c] = f2bf(ot * inv);
    }
  }
}

// ---------------- launch ---------------------------------------------------
extern "C" void kernel_launch(void* const* d_in, const int* in_sizes, int n_in,
                              void* d_out, int out_size, void* d_ws, size_t ws_size,
                              hipStream_t stream) {
  const float* x      = (const float*)d_in[0];
  const float* pos    = (const float*)d_in[1];
  const float* w_norm = (const float*)d_in[2];
  const float* w_in   = (const float*)d_in[3];
  const float* b_in   = (const float*)d_in[4];
  const float* w_out  = (const float*)d_in[5];
  const float* b_out  = (const float*)d_in[6];
  const float* b_coef = (const float*)d_in[7];
  const float* c_coef = (const float*)d_in[8];

  char* ws = (char*)d_ws;
  // ws layout (25.1 MB):
  //   [0, 6291456)        xn (bf16 8192x384); obuf overlays it (xn dead after GEMM1)
  //   [6291456, 7176192)  winb (bf16 1152x384)
  //   [7176192, 7471104)  woutb (bf16 384x384)
  //   [7471104, 26345472) qkv (bf16 8192x1152), Q pre-scaled by 1/8
  u16* xn    = (u16*)(ws + 0);
  u16* obuf  = (u16*)(ws + 0);          // overlays xn
  u16* winb  = (u16*)(ws + 6291456);
  u16* woutb = (u16*)(ws + 7176192);
  u16* qkvb  = (u16*)(ws + 7471104);

  prep_kernel<<<2336, 256, 0, stream>>>(x, w_norm, w_in, w_out, xn, winb, woutb);
  gemm_kernel<false, true><<<dim3(64, 9), 256, 0, stream>>>(
      xn, 384, winb, 384, b_in, qkvb, 1152, 384);
  attn_hybrid<<<768, 256, 0, stream>>>(qkvb, pos, b_coef, c_coef, obuf);
  gemm_kernel<true, false><<<dim3(64, 3), 256, 0, stream>>>(
      obuf, 384, woutb, 384, b_out, (float*)d_out, 384, 384);
}

// Round 6
// 507.963 us; speedup vs baseline: 4.5796x; 4.5796x over previous
//
#include <hip/hip_runtime.h>

// Problem: B=8, L=1024, C=384, H=6, D=64, K=2(radial), N=4(angular)
// R6: MFMA GEMMs (verified) + hybrid attention v2:
//     MFMA QK^T -> LDS S (verified) -> dim-split VALU PV (o[16]/thread, no spills).
typedef unsigned int  u32;
typedef unsigned short u16;
typedef __attribute__((ext_vector_type(8))) short short8;   // 8 bf16
typedef __attribute__((ext_vector_type(4))) float f32x4;

__device__ __forceinline__ u16 f2bf(float x) {
  union { float f; u32 u; } un; un.f = x;
  u32 r = un.u + 0x7FFFu + ((un.u >> 16) & 1u);   // RNE
  return (u16)(r >> 16);
}
__device__ __forceinline__ float bflo(u32 u) {
  union { u32 u; float f; } c; c.u = u << 16; return c.f;
}
__device__ __forceinline__ float bfhi(u32 u) {
  union { u32 u; float f; } c; c.u = u & 0xFFFF0000u; return c.f;
}
__device__ __forceinline__ f32x4 mfma_bf16(short8 a, short8 b, f32x4 c) {
  return __builtin_amdgcn_mfma_f32_16x16x32_bf16(a, b, c, 0, 0, 0);
}

// ---------------- prep: RMSNorm -> xn(bf16), convert w_in/w_out -> bf16 ----
__global__ __launch_bounds__(256) void prep_kernel(
    const float* __restrict__ x, const float* __restrict__ w_norm,
    const float* __restrict__ w_in, const float* __restrict__ w_out,
    u16* __restrict__ xn, u16* __restrict__ winb, u16* __restrict__ woutb)
{
  int blk = blockIdx.x, t = threadIdx.x;
  if (blk < 2048) {               // 8192 rows, 4 rows/block (1 per wave)
    int wv = t >> 6, lane = t & 63;
    int row = blk * 4 + wv;
    const float* xr = x + (size_t)row * 384;
    float v[6]; float ss = 0.f;
    #pragma unroll
    for (int i = 0; i < 6; i++) { v[i] = xr[lane + 64 * i]; ss += v[i] * v[i]; }
    #pragma unroll
    for (int off = 32; off > 0; off >>= 1) ss += __shfl_xor(ss, off);
    float rs = __builtin_amdgcn_rsqf(ss * (1.0f / 384.0f) + 1e-5f);
    #pragma unroll
    for (int i = 0; i < 6; i++) {
      float xv = v[i] * rs * w_norm[lane + 64 * i];
      xn[(size_t)row * 384 + lane + 64 * i] = f2bf(xv);
    }
  } else {                        // weight conversion: 442368 + 147456
    int base = (blk - 2048) * 2048 + t * 8;
    #pragma unroll
    for (int j = 0; j < 8; j++) {
      int idx = base + j;
      if (idx < 442368) winb[idx] = f2bf(w_in[idx]);
      else              woutb[idx - 442368] = f2bf(w_out[idx - 442368]);
    }
  }
}

// ---------------- MFMA GEMM: out[M,.] = A[M,K](lda)*Bw[N,K](ldb)^T + bias --
// 128x128 tile, BK=64, 4 waves (2x2), 16x16x32 bf16 MFMA, padded LDS. VERIFIED.
template<bool OUT_F32, bool QSCALE>
__global__ __launch_bounds__(256) void gemm_kernel(
    const u16* __restrict__ A, int lda,
    const u16* __restrict__ Bw, int ldb,
    const float* __restrict__ bias, void* __restrict__ outp, int ldc, int K)
{
  __shared__ __attribute__((aligned(16))) u16 As[128 * 72];
  __shared__ __attribute__((aligned(16))) u16 Bs[128 * 72];
  int t = threadIdx.x;
  int lane = t & 63, wv = t >> 6;
  int g = lane >> 4, cl = lane & 15;
  int row0 = blockIdx.x * 128, col0 = blockIdx.y * 128;
  int wm = (wv >> 1) * 64, wn = (wv & 1) * 64;
  f32x4 acc[4][4];
  #pragma unroll
  for (int i = 0; i < 4; i++)
    #pragma unroll
    for (int j = 0; j < 4; j++) acc[i][j] = (f32x4){0.f, 0.f, 0.f, 0.f};

  for (int k0 = 0; k0 < K; k0 += 64) {
    __syncthreads();
    #pragma unroll
    for (int j = 0; j < 4; j++) {
      int i = t + 256 * j;
      int r = i >> 3, ch = i & 7;
      *(uint4*)(&As[r * 72 + ch * 8]) =
          *(const uint4*)(A + (size_t)(row0 + r) * lda + k0 + ch * 8);
      *(uint4*)(&Bs[r * 72 + ch * 8]) =
          *(const uint4*)(Bw + (size_t)(col0 + r) * ldb + k0 + ch * 8);
    }
    __syncthreads();
    #pragma unroll
    for (int kh = 0; kh < 2; kh++) {
      short8 af[4], bfr[4];
      #pragma unroll
      for (int s = 0; s < 4; s++) {
        af[s]  = *(const short8*)(&As[(wm + s * 16 + cl) * 72 + kh * 32 + g * 8]);
        bfr[s] = *(const short8*)(&Bs[(wn + s * 16 + cl) * 72 + kh * 32 + g * 8]);
      }
      #pragma unroll
      for (int i = 0; i < 4; i++)
        #pragma unroll
        for (int j = 0; j < 4; j++)
          acc[i][j] = mfma_bf16(af[i], bfr[j], acc[i][j]);
    }
  }
  // epilogue: C/D layout col=lane&15, row=4*(lane>>4)+r  [HW-verified R4]
  #pragma unroll
  for (int i = 0; i < 4; i++) {
    #pragma unroll
    for (int j = 0; j < 4; j++) {
      int colb = col0 + wn + j * 16 + cl;
      float bv = bias[colb];
      #pragma unroll
      for (int r = 0; r < 4; r++) {
        int rowb = row0 + wm + i * 16 + g * 4 + r;
        float v = acc[i][j][r] + bv;
        if (QSCALE) { if (colb < 384) v *= 0.125f; }   // fold 1/sqrt(D) into Q
        if (OUT_F32) ((float*)outp)[(size_t)rowb * ldc + colb] = v;
        else ((u16*)outp)[(size_t)rowb * ldc + colb] = f2bf(v);
      }
    }
  }
}

// ---------------- hybrid attention v2 --------------------------------------
// Block = (b, h, 64 q-rows), 256 threads / 4 waves, 16 tiles of 64 keys.
// Phase 1 (MFMA, verified): wave wv computes S rows wv*16..+15 via QK^T MFMA,
//   adds polar bias at D-layout (row=4g+r, col=cl), stores f32 S to LDS.
// Phase 2 (VALU): thread (ql=t&63, dg=t>>6) owns q-row ql and dims dg*16..+15;
//   scans ALL 64 keys: online softmax (state duplicated across dg -- identical
//   by construction) + PV into o[16]. V loads are wave-uniform (broadcast).
__global__ __launch_bounds__(256) void attn_hybrid2(
    const u16* __restrict__ qkv, const float* __restrict__ pos,
    const float* __restrict__ bcf, const float* __restrict__ ccf,
    u16* __restrict__ obuf)
{
  __shared__ float sbuf[64][65];     // S tile (pad 65: 2-way banks on col reads)
  int blk = blockIdx.x;              // b*96 + h*16 + qt
  int qt = blk & 15, h = (blk >> 4) % 6, b = blk / 96;
  int t = threadIdx.x, lane = t & 63, wv = t >> 6;
  int g = lane >> 4, cl = lane & 15;
  int ql = t & 63, dg = t >> 6;      // phase-2 identity

  float bc[15], cc[15];
  #pragma unroll
  for (int i = 0; i < 15; i++) { bc[i] = bcf[h * 15 + i]; cc[i] = ccf[h * 15 + i]; }

  // Q fragments (A-operand): wave's rows wv*16+cl; Q pre-scaled by 1/8 in GEMM1
  const u16* qbase = qkv + (size_t)(b * 1024 + qt * 64 + wv * 16 + cl) * 1152 + h * 64;
  short8 qf0 = *(const short8*)(qbase + g * 8);
  short8 qf1 = *(const short8*)(qbase + 32 + g * 8);

  // bias q positions for this lane's output rows (4g+r within wave strip)
  float qx[4], qy[4];
  #pragma unroll
  for (int r = 0; r < 4; r++) {
    int qr = qt * 64 + wv * 16 + 4 * g + r;
    qx[r] = pos[(size_t)(b * 1024 + qr) * 2 + 0];
    qy[r] = pos[(size_t)(b * 1024 + qr) * 2 + 1];
  }

  // phase-2 private state: 16 dims only
  float o[16];
  #pragma unroll
  for (int c = 0; c < 16; c++) o[c] = 0.f;
  float m = -1e30f, l = 0.f;

  const u16* kb = qkv + (size_t)b * 1024 * 1152 + 384 + h * 64;
  const u16* vb = qkv + (size_t)b * 1024 * 1152 + 768 + h * 64 + dg * 16;
  const float* pb = pos + (size_t)b * 2048;

  for (int k0 = 0; k0 < 1024; k0 += 64) {
    // ---- phase 1: S = (Q/8)K^T + bias -> sbuf ----
    f32x4 s[4];
    #pragma unroll
    for (int ks = 0; ks < 4; ks++) {
      const u16* kr = kb + (size_t)(k0 + ks * 16 + cl) * 1152;
      short8 kf0 = *(const short8*)(kr + g * 8);
      short8 kf1 = *(const short8*)(kr + 32 + g * 8);
      f32x4 z = (f32x4){0.f, 0.f, 0.f, 0.f};
      z = mfma_bf16(qf0, kf0, z);
      z = mfma_bf16(qf1, kf1, z);
      s[ks] = z;
    }
    #pragma unroll
    for (int ks = 0; ks < 4; ks++) {
      int kidx = k0 + ks * 16 + cl;
      float kx = pb[kidx * 2], ky = pb[kidx * 2 + 1];
      #pragma unroll
      for (int r = 0; r < 4; r++) {
        float dx = qx[r] - kx, dy = qy[r] - ky;
        float r2 = dx * dx + dy * dy;
        bool zz = !(r2 > 0.f);
        float ir = zz ? 0.f : __builtin_amdgcn_rsqf(r2);
        float rr = r2 * ir;
        float c1 = zz ? 1.f : dx * ir;
        float s1 = dy * ir;
        float c2 = c1*c1 - s1*s1, s2 = 2.f*c1*s1;
        float c3 = c1*c2 - s1*s2, s3 = s1*c2 + c1*s2;
        float c4 = c2*c2 - s2*s2, s4 = 2.f*c2*s2;
        float a0 = bc[0] + bc[1]*c1 + bc[2]*c2 + bc[3]*c3 + bc[4]*c4
                 + cc[1]*s1 + cc[2]*s2 + cc[3]*s3 + cc[4]*s4;
        float a1 = bc[5] + bc[6]*c1 + bc[7]*c2 + bc[8]*c3 + bc[9]*c4
                 + cc[6]*s1 + cc[7]*s2 + cc[8]*s3 + cc[9]*s4;
        float a2 = bc[10] + bc[11]*c1 + bc[12]*c2 + bc[13]*c3 + bc[14]*c4
                 + cc[11]*s1 + cc[12]*s2 + cc[13]*s3 + cc[14]*s4;
        sbuf[wv * 16 + 4 * g + r][ks * 16 + cl] =
            s[ks][r] + a0 + rr * (a1 + rr * a2);
      }
    }
    __syncthreads();
    // ---- phase 2: online softmax + dim-split VALU PV over all 64 keys ----
    float tmax = -1e30f;
    #pragma unroll
    for (int j = 0; j < 64; j++) tmax = fmaxf(tmax, sbuf[ql][j]);
    float mn = fmaxf(m, tmax);
    float sc = __builtin_amdgcn_exp2f((m - mn) * 1.44269504f);
    m = mn;
    #pragma unroll
    for (int c = 0; c < 16; c++) o[c] *= sc;
    float psum = 0.f;
    #pragma unroll 8
    for (int j = 0; j < 64; j++) {
      float p = __builtin_amdgcn_exp2f((sbuf[ql][j] - mn) * 1.44269504f);
      psum += p;
      const uint4* vr = (const uint4*)(vb + (size_t)(k0 + j) * 1152);
      uint4 w0 = vr[0], w1 = vr[1];
      o[0]  += p * bflo(w0.x);  o[1]  += p * bfhi(w0.x);
      o[2]  += p * bflo(w0.y);  o[3]  += p * bfhi(w0.y);
      o[4]  += p * bflo(w0.z);  o[5]  += p * bfhi(w0.z);
      o[6]  += p * bflo(w0.w);  o[7]  += p * bfhi(w0.w);
      o[8]  += p * bflo(w1.x);  o[9]  += p * bfhi(w1.x);
      o[10] += p * bflo(w1.y);  o[11] += p * bfhi(w1.y);
      o[12] += p * bflo(w1.z);  o[13] += p * bfhi(w1.z);
      o[14] += p * bflo(w1.w);  o[15] += p * bfhi(w1.w);
    }
    l = l * sc + psum;
    __syncthreads();                 // sbuf reused next tile
  }
  // epilogue: thread writes its 16 dims (2x uint4 of packed bf16)
  float inv = __builtin_amdgcn_rcpf(l);
  u16* orow = obuf + (size_t)(b * 1024 + qt * 64 + ql) * 384 + h * 64 + dg * 16;
  union { u16 u[8]; uint4 v; } pk;
  #pragma unroll
  for (int c = 0; c < 8; c++) pk.u[c] = f2bf(o[c] * inv);
  *(uint4*)(orow) = pk.v;
  #pragma unroll
  for (int c = 0; c < 8; c++) pk.u[c] = f2bf(o[8 + c] * inv);
  *(uint4*)(orow + 8) = pk.v;
}

// ---------------- launch ---------------------------------------------------
extern "C" void kernel_launch(void* const* d_in, const int* in_sizes, int n_in,
                              void* d_out, int out_size, void* d_ws, size_t ws_size,
                              hipStream_t stream) {
  const float* x      = (const float*)d_in[0];
  const float* pos    = (const float*)d_in[1];
  const float* w_norm = (const float*)d_in[2];
  const float* w_in   = (const float*)d_in[3];
  const float* b_in   = (const float*)d_in[4];
  const float* w_out  = (const float*)d_in[5];
  const float* b_out  = (const float*)d_in[6];
  const float* b_coef = (const float*)d_in[7];
  const float* c_coef = (const float*)d_in[8];

  char* ws = (char*)d_ws;
  // ws layout (25.1 MB):
  //   [0, 6291456)        xn (bf16 8192x384); obuf overlays it (xn dead after GEMM1)
  //   [6291456, 7176192)  winb (bf16 1152x384)
  //   [7176192, 7471104)  woutb (bf16 384x384)
  //   [7471104, 26345472) qkv (bf16 8192x1152), Q pre-scaled by 1/8
  u16* xn    = (u16*)(ws + 0);
  u16* obuf  = (u16*)(ws + 0);          // overlays xn
  u16* winb  = (u16*)(ws + 6291456);
  u16* woutb = (u16*)(ws + 7176192);
  u16* qkvb  = (u16*)(ws + 7471104);

  prep_kernel<<<2336, 256, 0, stream>>>(x, w_norm, w_in, w_out, xn, winb, woutb);
  gemm_kernel<false, true><<<dim3(64, 9), 256, 0, stream>>>(
      xn, 384, winb, 384, b_in, qkvb, 1152, 384);
  attn_hybrid2<<<768, 256, 0, stream>>>(qkvb, pos, b_coef, c_coef, obuf);
  gemm_kernel<true, false><<<dim3(64, 3), 256, 0, stream>>>(
      obuf, 384, woutb, 384, b_out, (float*)d_out, 384, 384);
}

// Round 7
// 159.382 us; speedup vs baseline: 14.5956x; 3.1871x over previous
//
#include <hip/hip_runtime.h>

// Problem: B=8, L=1024, C=384, H=6, D=64, K=2(radial), N=4(angular)
// R7: MFMA GEMMs (verified) + full-MFMA attention:
//     QK^T MFMA + bias -> sbuf (verified) -> in-register P(bf16) A-frags ->
//     PV MFMA with V transposed per-tile into LDS (GEMM-B-analog layout).
typedef unsigned int  u32;
typedef unsigned short u16;
typedef __attribute__((ext_vector_type(8))) short short8;   // 8 bf16
typedef __attribute__((ext_vector_type(4))) float f32x4;

__device__ __forceinline__ u16 f2bf(float x) {
  union { float f; u32 u; } un; un.f = x;
  u32 r = un.u + 0x7FFFu + ((un.u >> 16) & 1u);   // RNE
  return (u16)(r >> 16);
}
__device__ __forceinline__ f32x4 mfma_bf16(short8 a, short8 b, f32x4 c) {
  return __builtin_amdgcn_mfma_f32_16x16x32_bf16(a, b, c, 0, 0, 0);
}

// ---------------- prep: RMSNorm -> xn(bf16), convert w_in/w_out -> bf16 ----
__global__ __launch_bounds__(256) void prep_kernel(
    const float* __restrict__ x, const float* __restrict__ w_norm,
    const float* __restrict__ w_in, const float* __restrict__ w_out,
    u16* __restrict__ xn, u16* __restrict__ winb, u16* __restrict__ woutb)
{
  int blk = blockIdx.x, t = threadIdx.x;
  if (blk < 2048) {               // 8192 rows, 4 rows/block (1 per wave)
    int wv = t >> 6, lane = t & 63;
    int row = blk * 4 + wv;
    const float* xr = x + (size_t)row * 384;
    float v[6]; float ss = 0.f;
    #pragma unroll
    for (int i = 0; i < 6; i++) { v[i] = xr[lane + 64 * i]; ss += v[i] * v[i]; }
    #pragma unroll
    for (int off = 32; off > 0; off >>= 1) ss += __shfl_xor(ss, off);
    float rs = __builtin_amdgcn_rsqf(ss * (1.0f / 384.0f) + 1e-5f);
    #pragma unroll
    for (int i = 0; i < 6; i++) {
      float xv = v[i] * rs * w_norm[lane + 64 * i];
      xn[(size_t)row * 384 + lane + 64 * i] = f2bf(xv);
    }
  } else {                        // weight conversion: 442368 + 147456
    int base = (blk - 2048) * 2048 + t * 8;
    #pragma unroll
    for (int j = 0; j < 8; j++) {
      int idx = base + j;
      if (idx < 442368) winb[idx] = f2bf(w_in[idx]);
      else              woutb[idx - 442368] = f2bf(w_out[idx - 442368]);
    }
  }
}

// ---------------- MFMA GEMM: out[M,.] = A[M,K](lda)*Bw[N,K](ldb)^T + bias --
// 128x128 tile, BK=64, 4 waves (2x2), 16x16x32 bf16 MFMA, padded LDS. VERIFIED.
template<bool OUT_F32, bool QSCALE>
__global__ __launch_bounds__(256) void gemm_kernel(
    const u16* __restrict__ A, int lda,
    const u16* __restrict__ Bw, int ldb,
    const float* __restrict__ bias, void* __restrict__ outp, int ldc, int K)
{
  __shared__ __attribute__((aligned(16))) u16 As[128 * 72];
  __shared__ __attribute__((aligned(16))) u16 Bs[128 * 72];
  int t = threadIdx.x;
  int lane = t & 63, wv = t >> 6;
  int g = lane >> 4, cl = lane & 15;
  int row0 = blockIdx.x * 128, col0 = blockIdx.y * 128;
  int wm = (wv >> 1) * 64, wn = (wv & 1) * 64;
  f32x4 acc[4][4];
  #pragma unroll
  for (int i = 0; i < 4; i++)
    #pragma unroll
    for (int j = 0; j < 4; j++) acc[i][j] = (f32x4){0.f, 0.f, 0.f, 0.f};

  for (int k0 = 0; k0 < K; k0 += 64) {
    __syncthreads();
    #pragma unroll
    for (int j = 0; j < 4; j++) {
      int i = t + 256 * j;
      int r = i >> 3, ch = i & 7;
      *(uint4*)(&As[r * 72 + ch * 8]) =
          *(const uint4*)(A + (size_t)(row0 + r) * lda + k0 + ch * 8);
      *(uint4*)(&Bs[r * 72 + ch * 8]) =
          *(const uint4*)(Bw + (size_t)(col0 + r) * ldb + k0 + ch * 8);
    }
    __syncthreads();
    #pragma unroll
    for (int kh = 0; kh < 2; kh++) {
      short8 af[4], bfr[4];
      #pragma unroll
      for (int s = 0; s < 4; s++) {
        af[s]  = *(const short8*)(&As[(wm + s * 16 + cl) * 72 + kh * 32 + g * 8]);
        bfr[s] = *(const short8*)(&Bs[(wn + s * 16 + cl) * 72 + kh * 32 + g * 8]);
      }
      #pragma unroll
      for (int i = 0; i < 4; i++)
        #pragma unroll
        for (int j = 0; j < 4; j++)
          acc[i][j] = mfma_bf16(af[i], bfr[j], acc[i][j]);
    }
  }
  // epilogue: C/D layout col=lane&15, row=4*(lane>>4)+r  [HW-verified R4]
  #pragma unroll
  for (int i = 0; i < 4; i++) {
    #pragma unroll
    for (int j = 0; j < 4; j++) {
      int colb = col0 + wn + j * 16 + cl;
      float bv = bias[colb];
      #pragma unroll
      for (int r = 0; r < 4; r++) {
        int rowb = row0 + wm + i * 16 + g * 4 + r;
        float v = acc[i][j][r] + bv;
        if (QSCALE) { if (colb < 384) v *= 0.125f; }   // fold 1/sqrt(D) into Q
        if (OUT_F32) ((float*)outp)[(size_t)rowb * ldc + colb] = v;
        else ((u16*)outp)[(size_t)rowb * ldc + colb] = f2bf(v);
      }
    }
  }
}

// ---------------- full-MFMA attention --------------------------------------
// Block = (b, h, 64 q-rows), 256 threads / 4 waves; wave wv owns q-rows
// wv*16..+15 end-to-end. 16 tiles of 64 keys:
//   V-stage: wave wv stages dims wv*16..+15 of the tile's V into vsmem[dim][key].
//   Phase 1 (verified): QK^T MFMA + polar bias -> sbuf f32 (D-layout rows).
//   Phase 2: per-wave online softmax (lane-owns-row reduce), P=exp packed to
//     bf16 A-frags in-register, PV via MFMA (B-frags = vsmem rows, GEMM-analog).
__global__ __launch_bounds__(256) void attn_hybrid3(
    const u16* __restrict__ qkv, const float* __restrict__ pos,
    const float* __restrict__ bcf, const float* __restrict__ ccf,
    u16* __restrict__ obuf)
{
  __shared__ __attribute__((aligned(16))) float sbuf[64][68];  // 17.4 KB
  __shared__ __attribute__((aligned(16))) u16 vsmem[64][72];   //  9.2 KB
  int blk = blockIdx.x;              // b*96 + h*16 + qt
  int qt = blk & 15, h = (blk >> 4) % 6, b = blk / 96;
  int t = threadIdx.x, lane = t & 63, wv = t >> 6;
  int g = lane >> 4, cl = lane & 15;

  float bc[15], cc[15];
  #pragma unroll
  for (int i = 0; i < 15; i++) { bc[i] = bcf[h * 15 + i]; cc[i] = ccf[h * 15 + i]; }

  // Q fragments (A-operand): rows wv*16+cl; Q pre-scaled by 1/8 in GEMM1
  const u16* qbase = qkv + (size_t)(b * 1024 + qt * 64 + wv * 16 + cl) * 1152 + h * 64;
  short8 qf0 = *(const short8*)(qbase + g * 8);
  short8 qf1 = *(const short8*)(qbase + 32 + g * 8);

  // bias q positions for this lane's S rows (4g+r within wave strip)
  float qx[4], qy[4];
  #pragma unroll
  for (int r = 0; r < 4; r++) {
    int qr = qt * 64 + wv * 16 + 4 * g + r;
    qx[r] = pos[(size_t)(b * 1024 + qr) * 2 + 0];
    qy[r] = pos[(size_t)(b * 1024 + qr) * 2 + 1];
  }

  // PV accumulators (D-layout: row=4g+r, col=d*16+cl) + softmax state
  // (lane owns row lane&15 of the wave strip; copies in all 4 lane-groups)
  f32x4 oa[4];
  #pragma unroll
  for (int d = 0; d < 4; d++) oa[d] = (f32x4){0.f, 0.f, 0.f, 0.f};
  float m_own = -1e30f, l_own = 0.f;

  const u16* kb = qkv + (size_t)b * 1024 * 1152 + 384 + h * 64;
  const u16* vsrc = qkv + (size_t)b * 1024 * 1152 + 768 + h * 64 + wv * 16;
  const float* pb = pos + (size_t)b * 2048;

  for (int k0 = 0; k0 < 1024; k0 += 64) {
    // ---- V-stage: vsmem[dim][key], wave wv handles dims wv*16..+15 ----
    {
      const u16* vr = vsrc + (size_t)(k0 + lane) * 1152;
      uint4 w0 = *(const uint4*)(vr);
      uint4 w1 = *(const uint4*)(vr + 8);
      int vd = wv * 16;
      vsmem[vd + 0][lane] = (u16)(w0.x);  vsmem[vd + 1][lane] = (u16)(w0.x >> 16);
      vsmem[vd + 2][lane] = (u16)(w0.y);  vsmem[vd + 3][lane] = (u16)(w0.y >> 16);
      vsmem[vd + 4][lane] = (u16)(w0.z);  vsmem[vd + 5][lane] = (u16)(w0.z >> 16);
      vsmem[vd + 6][lane] = (u16)(w0.w);  vsmem[vd + 7][lane] = (u16)(w0.w >> 16);
      vsmem[vd + 8][lane] = (u16)(w1.x);  vsmem[vd + 9][lane] = (u16)(w1.x >> 16);
      vsmem[vd +10][lane] = (u16)(w1.y);  vsmem[vd +11][lane] = (u16)(w1.y >> 16);
      vsmem[vd +12][lane] = (u16)(w1.z);  vsmem[vd +13][lane] = (u16)(w1.z >> 16);
      vsmem[vd +14][lane] = (u16)(w1.w);  vsmem[vd +15][lane] = (u16)(w1.w >> 16);
    }
    // ---- phase 1 (verified): S = (Q/8)K^T + bias -> sbuf ----
    f32x4 s[4];
    #pragma unroll
    for (int ks = 0; ks < 4; ks++) {
      const u16* kr = kb + (size_t)(k0 + ks * 16 + cl) * 1152;
      short8 kf0 = *(const short8*)(kr + g * 8);
      short8 kf1 = *(const short8*)(kr + 32 + g * 8);
      f32x4 z = (f32x4){0.f, 0.f, 0.f, 0.f};
      z = mfma_bf16(qf0, kf0, z);
      z = mfma_bf16(qf1, kf1, z);
      s[ks] = z;
    }
    #pragma unroll
    for (int ks = 0; ks < 4; ks++) {
      int kidx = k0 + ks * 16 + cl;
      float kx = pb[kidx * 2], ky = pb[kidx * 2 + 1];
      #pragma unroll
      for (int r = 0; r < 4; r++) {
        float dx = qx[r] - kx, dy = qy[r] - ky;
        float r2 = dx * dx + dy * dy;
        bool zz = !(r2 > 0.f);
        float ir = zz ? 0.f : __builtin_amdgcn_rsqf(r2);
        float rr = r2 * ir;
        float c1 = zz ? 1.f : dx * ir;
        float s1 = dy * ir;
        float c2 = c1*c1 - s1*s1, s2 = 2.f*c1*s1;
        float c3 = c1*c2 - s1*s2, s3 = s1*c2 + c1*s2;
        float c4 = c2*c2 - s2*s2, s4 = 2.f*c2*s2;
        float a0 = bc[0] + bc[1]*c1 + bc[2]*c2 + bc[3]*c3 + bc[4]*c4
                 + cc[1]*s1 + cc[2]*s2 + cc[3]*s3 + cc[4]*s4;
        float a1 = bc[5] + bc[6]*c1 + bc[7]*c2 + bc[8]*c3 + bc[9]*c4
                 + cc[6]*s1 + cc[7]*s2 + cc[8]*s3 + cc[9]*s4;
        float a2 = bc[10] + bc[11]*c1 + bc[12]*c2 + bc[13]*c3 + bc[14]*c4
                 + cc[11]*s1 + cc[12]*s2 + cc[13]*s3 + cc[14]*s4;
        sbuf[wv * 16 + 4 * g + r][ks * 16 + cl] =
            s[ks][r] + a0 + rr * (a1 + rr * a2);
      }
    }
    __syncthreads();
    // ---- phase 2: per-wave softmax + MFMA PV ----
    // (a) row max: lane owns row (lane&15), scans cols (lane>>4)*16..+15
    {
      int rown = wv * 16 + (lane & 15), cb = (lane >> 4) * 16;
      float tmax = -1e30f;
      #pragma unroll
      for (int c = 0; c < 16; c++) tmax = fmaxf(tmax, sbuf[rown][cb + c]);
      tmax = fmaxf(tmax, __shfl_xor(tmax, 16));
      tmax = fmaxf(tmax, __shfl_xor(tmax, 32));
      float mn = fmaxf(m_own, tmax);
      float sc = __builtin_amdgcn_exp2f((m_own - mn) * 1.44269504f);
      m_own = mn;
      float mrow = __shfl(mn, cl);           // new max for row cl
      // (b) rescale O (rows 4g+r)
      #pragma unroll
      for (int r = 0; r < 4; r++) {
        float scr = __shfl(sc, 4 * g + r);
        #pragma unroll
        for (int d = 0; d < 4; d++) oa[d][r] *= scr;
      }
      // (c) P A-fragments in-register (row=cl, k=kh*32+8g+j) + psum
      float psum = 0.f;
      union { u16 u[8]; short8 s8; } pk0, pk1;
      const float* srow = &sbuf[wv * 16 + cl][0];
      #pragma unroll
      for (int j = 0; j < 8; j++) {
        float p = __builtin_amdgcn_exp2f((srow[8 * g + j] - mrow) * 1.44269504f);
        psum += p; pk0.u[j] = f2bf(p);
      }
      #pragma unroll
      for (int j = 0; j < 8; j++) {
        float p = __builtin_amdgcn_exp2f((srow[32 + 8 * g + j] - mrow) * 1.44269504f);
        psum += p; pk1.u[j] = f2bf(p);
      }
      psum += __shfl_xor(psum, 16);
      psum += __shfl_xor(psum, 32);          // full row-cl sum at every lane
      l_own = l_own * sc + psum;             // lane's own row == cl (lane&15)
      // (d) PV MFMA: B-frag rows of vsmem (GEMM-B analog)
      #pragma unroll
      for (int d = 0; d < 4; d++) {
        short8 vf0 = *(const short8*)(&vsmem[d * 16 + cl][g * 8]);
        short8 vf1 = *(const short8*)(&vsmem[d * 16 + cl][32 + g * 8]);
        oa[d] = mfma_bf16(pk0.s8, vf0, oa[d]);
        oa[d] = mfma_bf16(pk1.s8, vf1, oa[d]);
      }
    }
    __syncthreads();                         // sbuf/vsmem reused next tile
  }
  // epilogue: normalize + write (D-layout rows 4g+r, cols d*16+cl)
  float inv = __builtin_amdgcn_rcpf(l_own);
  #pragma unroll
  for (int r = 0; r < 4; r++) {
    float invr = __shfl(inv, 4 * g + r);
    int qr = qt * 64 + wv * 16 + 4 * g + r;
    #pragma unroll
    for (int d = 0; d < 4; d++) {
      obuf[(size_t)(b * 1024 + qr) * 384 + h * 64 + d * 16 + cl] =
          f2bf(oa[d][r] * invr);
    }
  }
}

// ---------------- launch ---------------------------------------------------
extern "C" void kernel_launch(void* const* d_in, const int* in_sizes, int n_in,
                              void* d_out, int out_size, void* d_ws, size_t ws_size,
                              hipStream_t stream) {
  const float* x      = (const float*)d_in[0];
  const float* pos    = (const float*)d_in[1];
  const float* w_norm = (const float*)d_in[2];
  const float* w_in   = (const float*)d_in[3];
  const float* b_in   = (const float*)d_in[4];
  const float* w_out  = (const float*)d_in[5];
  const float* b_out  = (const float*)d_in[6];
  const float* b_coef = (const float*)d_in[7];
  const float* c_coef = (const float*)d_in[8];

  char* ws = (char*)d_ws;
  // ws layout (25.1 MB):
  //   [0, 6291456)        xn (bf16 8192x384); obuf overlays it (xn dead after GEMM1)
  //   [6291456, 7176192)  winb (bf16 1152x384)
  //   [7176192, 7471104)  woutb (bf16 384x384)
  //   [7471104, 26345472) qkv (bf16 8192x1152), Q pre-scaled by 1/8
  u16* xn    = (u16*)(ws + 0);
  u16* obuf  = (u16*)(ws + 0);          // overlays xn
  u16* winb  = (u16*)(ws + 6291456);
  u16* woutb = (u16*)(ws + 7176192);
  u16* qkvb  = (u16*)(ws + 7471104);

  prep_kernel<<<2336, 256, 0, stream>>>(x, w_norm, w_in, w_out, xn, winb, woutb);
  gemm_kernel<false, true><<<dim3(64, 9), 256, 0, stream>>>(
      xn, 384, winb, 384, b_in, qkvb, 1152, 384);
  attn_hybrid3<<<768, 256, 0, stream>>>(qkvb, pos, b_coef, c_coef, obuf);
  gemm_kernel<true, false><<<dim3(64, 3), 256, 0, stream>>>(
      obuf, 384, woutb, 384, b_out, (float*)d_out, 384, 384);
}